// Round 1
// baseline (2400.466 us; speedup 1.0000x reference)
//
#include <hip/hip_runtime.h>
#include <math.h>

// MomentLayerRecurrent on MI355X — round 0: correct fp32 implementation.
// B=32, N=512, SEQ=8. Dominant cost: per step, per batch: T1 = (W*diag(s))@rho,
// rho_out = (T1*diag(s))@W^T with fused normalization epilogue.
// Dawson-style tables built on-device in fp64 each launch (1 wave, chunked scans).

#define BB 32
#define NN 512
#define SEQ 8
#define TG 7001

#define TILE 128
#define BK 16

// ---------------- table interpolation (uniform grid [-10,4], dx=0.002) -------
__device__ __forceinline__ float interp_tab(const float* __restrict__ tab, float x) {
    float t = (x + 10.0f) * 500.0f;          // 1/dx = 500
    t = fminf(fmaxf(t, 0.0f), 7000.0f);
    int i0 = (int)t;
    if (i0 > 6999) i0 = 6999;
    float fr = t - (float)i0;
    float a = tab[i0];
    float b = tab[i0 + 1];
    return a + fr * (b - a);
}

// ---------------- Dawson-table build: one wave, 4 chained cumtrapz scans -----
__global__ void k_tables(double* __restrict__ D1, double* __restrict__ D2,
                         float* __restrict__ GT, float* __restrict__ GI,
                         float* __restrict__ HI) {
    const int lane = threadIdx.x;            // block = 64 (one wave)
    const double dx = 14.0 / 7000.0;
    const int CH = 110;                      // 64*110 = 7040 >= 7001
    int k0 = lane * CH;
    int k1 = k0 + CH; if (k1 > TG) k1 = TG;
    if (k0 > TG) k0 = TG;

    // phase 1: I = exp(-100)/20 + cumtrapz(exp(-x^2));  g = exp(x^2)*I
    {
        double part = 0.0;
        for (int k = (k0 < 1 ? 1 : k0); k < k1; ++k) {
            double xa = -10.0 + dx * (k - 1), xb = -10.0 + dx * k;
            part += 0.5 * (exp(-xa * xa) + exp(-xb * xb)) * dx;
        }
        double run = part;
        #pragma unroll
        for (int off = 1; off < 64; off <<= 1) {
            double n = __shfl_up(run, off);
            if (lane >= off) run += n;
        }
        run -= part;                          // exclusive prefix
        run += exp(-100.0) / 20.0;
        for (int k = k0; k < k1; ++k) {
            if (k >= 1) {
                double xa = -10.0 + dx * (k - 1), xb = -10.0 + dx * k;
                run += 0.5 * (exp(-xa * xa) + exp(-xb * xb)) * dx;
            }
            double x = -10.0 + dx * k;
            double g = exp(x * x) * run;
            D2[k] = g;
            GT[k] = (float)g;
        }
    }
    __syncthreads();
    // phase 2: G = cumtrapz(g)
    {
        double part = 0.0;
        for (int k = (k0 < 1 ? 1 : k0); k < k1; ++k)
            part += 0.5 * (D2[k - 1] + D2[k]) * dx;
        double run = part;
        #pragma unroll
        for (int off = 1; off < 64; off <<= 1) {
            double n = __shfl_up(run, off);
            if (lane >= off) run += n;
        }
        run -= part;
        for (int k = k0; k < k1; ++k) {
            if (k >= 1) run += 0.5 * (D2[k - 1] + D2[k]) * dx;
            GI[k] = (float)run;
        }
    }
    __syncthreads();
    // phase 3: E = cumtrapz(exp(-x^2) * g^2)
    {
        double part = 0.0;
        for (int k = (k0 < 1 ? 1 : k0); k < k1; ++k) {
            double xa = -10.0 + dx * (k - 1), xb = -10.0 + dx * k;
            double ga = D2[k - 1], gb = D2[k];
            part += 0.5 * (exp(-xa * xa) * ga * ga + exp(-xb * xb) * gb * gb) * dx;
        }
        double run = part;
        #pragma unroll
        for (int off = 1; off < 64; off <<= 1) {
            double n = __shfl_up(run, off);
            if (lane >= off) run += n;
        }
        run -= part;
        for (int k = k0; k < k1; ++k) {
            if (k >= 1) {
                double xa = -10.0 + dx * (k - 1), xb = -10.0 + dx * k;
                double ga = D2[k - 1], gb = D2[k];
                run += 0.5 * (exp(-xa * xa) * ga * ga + exp(-xb * xb) * gb * gb) * dx;
            }
            D1[k] = run;
        }
    }
    __syncthreads();
    // phase 4: H = cumtrapz(exp(x^2) * E)
    {
        double part = 0.0;
        for (int k = (k0 < 1 ? 1 : k0); k < k1; ++k) {
            double xa = -10.0 + dx * (k - 1), xb = -10.0 + dx * k;
            part += 0.5 * (exp(xa * xa) * D1[k - 1] + exp(xb * xb) * D1[k]) * dx;
        }
        double run = part;
        #pragma unroll
        for (int off = 1; off < 64; off <<= 1) {
            double n = __shfl_up(run, off);
            if (lane >= off) run += n;
        }
        run -= part;
        for (int k = k0; k < k1; ++k) {
            if (k >= 1) {
                double xa = -10.0 + dx * (k - 1), xb = -10.0 + dx * k;
                run += 0.5 * (exp(xa * xa) * D1[k - 1] + exp(xb * xb) * D1[k]) * dx;
            }
            HI[k] = (float)run;
        }
    }
}

// ---------------- batched fp32 GEMM, 128x128 tile, BK=16, 8x8 per thread -----
// C[b] = (A[b]*diag(sv[b])) @ B[b]      (TRANSB=0: B[k][n] = Bm[k*N+n])
//                                       (TRANSB=1: B[k][n] = Bm[n*N+k])
// EPI=1: rho-normalization epilogue using s_lin (sqrt diag C) and chi.
template <bool TRANSB, bool EPI>
__global__ __launch_bounds__(256)
void gemm128(const float* __restrict__ A, long aStride,
             const float* __restrict__ Bm, long bStride,
             float* __restrict__ C,
             const float* __restrict__ svec,
             const float* __restrict__ s_lin,
             const float* __restrict__ chi) {
    __shared__ __align__(16) float As[BK][TILE];
    __shared__ __align__(16) float Bs[BK][TILE];
    const int b  = blockIdx.z;
    const int i0 = blockIdx.y * TILE;
    const int j0 = blockIdx.x * TILE;
    const int tid = threadIdx.x;
    const int tx = tid & 15, ty = tid >> 4;
    const float* __restrict__ Ab = A + (long)b * aStride;
    const float* __restrict__ Bb = Bm + (long)b * bStride;
    const float* __restrict__ sv = svec + b * NN;

    float acc[8][8];
    #pragma unroll
    for (int r = 0; r < 8; ++r)
        #pragma unroll
        for (int c = 0; c < 8; ++c) acc[r][c] = 0.0f;

    for (int k0 = 0; k0 < NN; k0 += BK) {
        // A tile: scale columns by sv, store transposed As[k][m]
        #pragma unroll
        for (int it = 0; it < 2; ++it) {
            int idx = tid + it * 256;
            int row = idx >> 2;               // 0..127
            int kq  = (idx & 3) * 4;
            const float4 v = *reinterpret_cast<const float4*>(
                Ab + (long)(i0 + row) * NN + k0 + kq);
            As[kq + 0][row] = v.x * sv[k0 + kq + 0];
            As[kq + 1][row] = v.y * sv[k0 + kq + 1];
            As[kq + 2][row] = v.z * sv[k0 + kq + 2];
            As[kq + 3][row] = v.w * sv[k0 + kq + 3];
        }
        // B tile
        if (!TRANSB) {
            #pragma unroll
            for (int it = 0; it < 2; ++it) {
                int idx = tid + it * 256;
                int kk = idx >> 5;            // 0..15
                int q  = idx & 31;
                float4 v = *reinterpret_cast<const float4*>(
                    Bb + (long)(k0 + kk) * NN + j0 + q * 4);
                *reinterpret_cast<float4*>(&Bs[kk][q * 4]) = v;
            }
        } else {
            #pragma unroll
            for (int it = 0; it < 2; ++it) {
                int idx = tid + it * 256;
                int row = idx >> 2;           // n: 0..127
                int kq  = (idx & 3) * 4;
                const float4 v = *reinterpret_cast<const float4*>(
                    Bb + (long)(j0 + row) * NN + k0 + kq);
                Bs[kq + 0][row] = v.x;
                Bs[kq + 1][row] = v.y;
                Bs[kq + 2][row] = v.z;
                Bs[kq + 3][row] = v.w;
            }
        }
        __syncthreads();
        #pragma unroll
        for (int kk = 0; kk < BK; ++kk) {
            float4 a0 = *reinterpret_cast<const float4*>(&As[kk][ty * 8]);
            float4 a1 = *reinterpret_cast<const float4*>(&As[kk][ty * 8 + 4]);
            float4 b0 = *reinterpret_cast<const float4*>(&Bs[kk][tx * 8]);
            float4 b1 = *reinterpret_cast<const float4*>(&Bs[kk][tx * 8 + 4]);
            float av[8] = {a0.x, a0.y, a0.z, a0.w, a1.x, a1.y, a1.z, a1.w};
            float bv[8] = {b0.x, b0.y, b0.z, b0.w, b1.x, b1.y, b1.z, b1.w};
            #pragma unroll
            for (int r = 0; r < 8; ++r)
                #pragma unroll
                for (int c = 0; c < 8; ++c)
                    acc[r][c] = fmaf(av[r], bv[c], acc[r][c]);
        }
        __syncthreads();
    }

    float* __restrict__ Cb = C + (long)b * NN * NN;
    if (!EPI) {
        #pragma unroll
        for (int r = 0; r < 8; ++r) {
            int i = i0 + ty * 8 + r;
            float4 v0 = make_float4(acc[r][0], acc[r][1], acc[r][2], acc[r][3]);
            float4 v1 = make_float4(acc[r][4], acc[r][5], acc[r][6], acc[r][7]);
            *reinterpret_cast<float4*>(Cb + (long)i * NN + j0 + tx * 8)     = v0;
            *reinterpret_cast<float4*>(Cb + (long)i * NN + j0 + tx * 8 + 4) = v1;
        }
    } else {
        const float* sl = s_lin + b * NN;
        const float* ch = chi + b * NN;
        float sj[8], cj[8];
        #pragma unroll
        for (int c = 0; c < 8; ++c) {
            int j = j0 + tx * 8 + c;
            sj[c] = sl[j];
            cj[c] = ch[j];
        }
        #pragma unroll
        for (int r = 0; r < 8; ++r) {
            int i = i0 + ty * 8 + r;
            float si = sl[i], ci = ch[i];
            float outv[8];
            #pragma unroll
            for (int c = 0; c < 8; ++c) {
                int j = j0 + tx * 8 + c;
                float denom = si * sj[c];
                float v = (denom > 1e-12f) ? (acc[r][c] / denom) : 0.0f;
                v *= ci * cj[c];
                if (i == j) v = 1.0f;
                outv[c] = v;
            }
            float4 v0 = make_float4(outv[0], outv[1], outv[2], outv[3]);
            float4 v1 = make_float4(outv[4], outv[5], outv[6], outv[7]);
            *reinterpret_cast<float4*>(Cb + (long)i * NN + j0 + tx * 8)     = v0;
            *reinterpret_cast<float4*>(Cb + (long)i * NN + j0 + tx * 8 + 4) = v1;
        }
    }
}

// ---------------- external pathway: wave-per-(b,i) dots ----------------------
__global__ void k_ext_dots(const float* __restrict__ Wx, const float* __restrict__ bx,
                           const float* __restrict__ ux, const float* __restrict__ sx,
                           float* __restrict__ u_e, float* __restrict__ s_e2) {
    int gw = (blockIdx.x << 2) + (threadIdx.x >> 6);
    int lane = threadIdx.x & 63;
    int b = gw >> 9, i = gw & 511;
    const float* wr = Wx + (long)i * NN;
    const float* ub = ux + b * NN;
    const float* sb = sx + b * NN;
    float au = 0.0f, as2 = 0.0f;
    for (int j = lane; j < NN; j += 64) {
        float w = wr[j];
        float s = sb[j];
        au  = fmaf(w, ub[j], au);
        as2 = fmaf(w * w, s * s, as2);
    }
    #pragma unroll
    for (int off = 32; off; off >>= 1) {
        au  += __shfl_down(au, off);
        as2 += __shfl_down(as2, off);
    }
    if (lane == 0) {
        u_e[b * NN + i]  = au + bx[i];
        s_e2[b * NN + i] = as2;
    }
}

__global__ void k_ext_stats(float* __restrict__ u_e, float* __restrict__ s_e2,
                            const float* __restrict__ wmx, const float* __restrict__ bmx) {
    int i = blockIdx.x * blockDim.x + threadIdx.x;
    if (i >= NN) return;
    float m = 0.0f;
    for (int b = 0; b < BB; ++b) m += u_e[b * NN + i];
    m *= (1.0f / BB);
    float v = 0.0f;
    for (int b = 0; b < BB; ++b) {
        float d = u_e[b * NN + i] - m;
        v = fmaf(d, d, v);
    }
    v *= (1.0f / BB);
    float f = wmx[i] / sqrtf(v + 1e-5f);
    float bm = bmx[i];
    for (int b = 0; b < BB; ++b) {
        u_e[b * NN + i]  = (u_e[b * NN + i] - m) * f + bm;
        s_e2[b * NN + i] *= f * f;
    }
}

// ---------------- per-step: u_lin + diag(C) (wave per (b,i)) -----------------
__global__ void k_dots(const float* __restrict__ W, const float* __restrict__ bvec,
                       const float* __restrict__ u, const float* __restrict__ s,
                       const float* __restrict__ T1,
                       float* __restrict__ u_lin, float* __restrict__ s_lin) {
    int gw = (blockIdx.x << 2) + (threadIdx.x >> 6);
    int lane = threadIdx.x & 63;
    int b = gw >> 9, i = gw & 511;
    const float* wr = W + (long)i * NN;
    const float* ub = u + b * NN;
    const float* sb = s + b * NN;
    const float* t1 = T1 + ((long)b * NN + i) * NN;
    float au = 0.0f, ad = 0.0f;
    for (int j = lane; j < NN; j += 64) {
        float w = wr[j];
        au = fmaf(w, ub[j], au);
        ad = fmaf(w * sb[j], t1[j], ad);
    }
    #pragma unroll
    for (int off = 32; off; off >>= 1) {
        au += __shfl_down(au, off);
        ad += __shfl_down(ad, off);
    }
    if (lane == 0) {
        u_lin[b * NN + i] = au + bvec[i];
        s_lin[b * NN + i] = sqrtf(fmaxf(ad, 0.0f));   // clip(var,0)
    }
}

__global__ void k_stats(const float* __restrict__ u_lin, const float* __restrict__ wm,
                        float* __restrict__ bn_mean, float* __restrict__ bn_f) {
    int i = blockIdx.x * blockDim.x + threadIdx.x;
    if (i >= NN) return;
    float m = 0.0f;
    for (int b = 0; b < BB; ++b) m += u_lin[b * NN + i];
    m *= (1.0f / BB);
    float v = 0.0f;
    for (int b = 0; b < BB; ++b) {
        float d = u_lin[b * NN + i] - m;
        v = fmaf(d, d, v);
    }
    v *= (1.0f / BB);
    bn_mean[i] = m;
    bn_f[i] = wm[i] / sqrtf(v + 1e-5f);
}

// ---------------- BN apply + ext merge + LIF moment activation ---------------
__global__ void k_act(const float* __restrict__ u_lin, const float* __restrict__ s_lin,
                      const float* __restrict__ bn_mean, const float* __restrict__ bn_f,
                      const float* __restrict__ b_mean,
                      const float* __restrict__ u_e, const float* __restrict__ s_e2,
                      const float* __restrict__ GT, const float* __restrict__ GI,
                      const float* __restrict__ HI,
                      float* __restrict__ u_out, float* __restrict__ s_out,
                      float* __restrict__ chi) {
    int idx = blockIdx.x * blockDim.x + threadIdx.x;   // 0..16383
    int i = idx & 511;
    const float SQL = 0.22360679774997896f;            // sqrt(0.05)
    float f  = bn_f[i];
    float un = (u_lin[idx] - bn_mean[i]) * f + b_mean[i] + u_e[idx];
    float sl = s_lin[idx];
    float sn = sqrtf(sl * sl * f * f + s_e2[idx]);     // sqrt((s*|f|)^2 + s_e^2)
    float ss = fmaxf(sn, 1e-6f);
    float inv = 1.0f / (ss * SQL);
    float ubx = fminf(fmaxf((1.0f - un) * inv, -10.0f), 4.0f);  // V_TH*L = 1
    float lbx = fminf(fmaxf((0.0f - un) * inv, -10.0f), 4.0f);  // V_RES*L = 0
    float dG = interp_tab(GI, ubx) - interp_tab(GI, lbx);
    float ua = 1.0f / (5.0f + 40.0f * dG);             // T_REF + (2/L)dG
    float dH = fmaxf(interp_tab(HI, ubx) - interp_tab(HI, lbx), 0.0f);
    float sa = sqrtf(3200.0f * dH * ua * ua * ua);     // 8/L^2 = 3200
    float dg = interp_tab(GT, ubx) - interp_tab(GT, lbx);
    float ch = ua * ua * 40.0f * dg / (SQL * fmaxf(sa, 1e-9f));
    u_out[idx] = ua;
    s_out[idx] = sa;
    chi[idx] = ch;
}

// ---------------- launcher ---------------------------------------------------
extern "C" void kernel_launch(void* const* d_in, const int* in_sizes, int n_in,
                              void* d_out, int out_size, void* d_ws, size_t ws_size,
                              hipStream_t stream) {
    (void)in_sizes; (void)n_in; (void)out_size; (void)ws_size;
    const float* u_in       = (const float*)d_in[0];
    const float* s_in       = (const float*)d_in[1];
    const float* rho_in     = (const float*)d_in[2];
    const float* u_ext      = (const float*)d_in[3];
    const float* s_ext      = (const float*)d_in[4];
    const float* W          = (const float*)d_in[5];
    const float* bvec       = (const float*)d_in[6];
    const float* W_ext      = (const float*)d_in[7];
    const float* b_ext      = (const float*)d_in[8];
    const float* w_mean     = (const float*)d_in[9];
    const float* b_mean     = (const float*)d_in[10];
    const float* w_mean_ext = (const float*)d_in[11];
    const float* b_mean_ext = (const float*)d_in[12];
    // d_in[13] = seq_len (=8, hardcoded)

    float* out_u   = (float*)d_out;
    float* out_s   = out_u + BB * NN;
    float* out_rho = out_s + BB * NN;

    char* base = (char*)d_ws;
    size_t off = 0;
    auto alloc = [&](size_t bytes) -> char* {
        char* p = base + off;
        off += (bytes + 255) & ~(size_t)255;
        return p;
    };
    float*  T1    = (float*)alloc((size_t)BB * NN * NN * 4);   // 33.5 MB
    double* D1    = (double*)alloc(TG * 8);
    double* D2    = (double*)alloc(TG * 8);
    float*  GTt   = (float*)alloc(TG * 4);
    float*  GIt   = (float*)alloc(TG * 4);
    float*  HIt   = (float*)alloc(TG * 4);
    float*  u_e   = (float*)alloc(BB * NN * 4);
    float*  s_e2  = (float*)alloc(BB * NN * 4);
    float*  uA    = (float*)alloc(BB * NN * 4);
    float*  uB2   = (float*)alloc(BB * NN * 4);
    float*  sA    = (float*)alloc(BB * NN * 4);
    float*  sB2   = (float*)alloc(BB * NN * 4);
    float*  u_lin = (float*)alloc(BB * NN * 4);
    float*  s_lin = (float*)alloc(BB * NN * 4);
    float*  chi_  = (float*)alloc(BB * NN * 4);
    float*  bn_m  = (float*)alloc(NN * 4);
    float*  bn_f  = (float*)alloc(NN * 4);

    // prologue: tables + external pathway
    k_tables<<<1, 64, 0, stream>>>(D1, D2, GTt, GIt, HIt);
    k_ext_dots<<<BB * NN / 4, 256, 0, stream>>>(W_ext, b_ext, u_ext, s_ext, u_e, s_e2);
    k_ext_stats<<<2, 256, 0, stream>>>(u_e, s_e2, w_mean_ext, b_mean_ext);

    const float* cu = u_in;
    const float* cs = s_in;
    const float* crho = rho_in;
    dim3 gg(NN / TILE, NN / TILE, BB);   // 4 x 4 x 32

    for (int t = 0; t < SEQ; ++t) {
        // T1 = (W*diag(s)) @ rho
        gemm128<false, false><<<gg, 256, 0, stream>>>(
            W, 0L, crho, (long)NN * NN, T1, cs, nullptr, nullptr);
        // u_lin = u@W^T + b ; s_lin = sqrt(max(diag(C),0))
        k_dots<<<BB * NN / 4, 256, 0, stream>>>(W, bvec, cu, cs, T1, u_lin, s_lin);
        // BN stats over batch
        k_stats<<<2, 256, 0, stream>>>(u_lin, w_mean, bn_m, bn_f);
        // BN apply + ext + moment activation -> ua, sa, chi
        float* nu = (t == SEQ - 1) ? out_u : ((t & 1) ? uA : uB2);
        float* ns = (t == SEQ - 1) ? out_s : ((t & 1) ? sA : sB2);
        k_act<<<BB * NN / 256, 256, 0, stream>>>(
            u_lin, s_lin, bn_m, bn_f, b_mean, u_e, s_e2, GTt, GIt, HIt, nu, ns, chi_);
        // rho_out = epi( (T1*diag(s)) @ W^T )  — written in place in d_out
        gemm128<true, true><<<gg, 256, 0, stream>>>(
            T1, (long)NN * NN, W, 0L, out_rho, cs, s_lin, chi_);
        cu = nu; cs = ns; crho = out_rho;
    }
}

// Round 2
// 833.855 us; speedup vs baseline: 2.8788x; 2.8788x over previous
//
#include <hip/hip_runtime.h>
#include <math.h>

// MomentLayerRecurrent — round 2: split-2 bf16 MFMA GEMMs (hi+lo, 3 products),
// Q = diag(s) rho diag(s) propagated so W is the static A/B^T operand.
// GEMM1: T1 = W @ Q (Q symmetric => row-major Q serves as B^T).
// GEMM2: C = T1 @ W^T; epilogue produces rho and writes Q_next split-bf16
// (s_next known since activation runs before GEMM2), or fp32 rho on last step.

#define BB 32
#define NN 512
#define SEQ 8
#define TG 7001

typedef float f32x4 __attribute__((ext_vector_type(4)));
typedef short s16x8 __attribute__((ext_vector_type(8)));

#define GL16(g, l) __builtin_amdgcn_global_load_lds( \
    (const __attribute__((address_space(1))) void*)(g), \
    (__attribute__((address_space(3))) void*)(l), 16, 0, 0)

__device__ __forceinline__ unsigned short bf16_rne(float v) {
    unsigned u = __float_as_uint(v);
    u += 0x7FFFu + ((u >> 16) & 1u);
    return (unsigned short)(u >> 16);
}
__device__ __forceinline__ float bf16_f(unsigned short h) {
    return __uint_as_float(((unsigned)h) << 16);
}
__device__ __forceinline__ void split2(float v, unsigned short& h, unsigned short& l) {
    unsigned short hh = bf16_rne(v);
    h = hh;
    l = bf16_rne(v - bf16_f(hh));
}

// ---------------- table interpolation (uniform grid [-10,4], dx=0.002) -------
__device__ __forceinline__ float interp_tab(const float* __restrict__ tab, float x) {
    float t = (x + 10.0f) * 500.0f;
    t = fminf(fmaxf(t, 0.0f), 7000.0f);
    int i0 = (int)t;
    if (i0 > 6999) i0 = 6999;
    float fr = t - (float)i0;
    float a = tab[i0];
    float b = tab[i0 + 1];
    return a + fr * (b - a);
}

// ---------------- Dawson tables: 1 block x 1024 threads, hierarchical scans --
__device__ double blk_exscan(double part, double* wsum) {
    int t = threadIdx.x, lane = t & 63, wid = t >> 6;
    double run = part;
    #pragma unroll
    for (int off = 1; off < 64; off <<= 1) {
        double nv = __shfl_up(run, off);
        if (lane >= off) run += nv;
    }
    if (lane == 63) wsum[wid] = run;
    __syncthreads();
    if (t < 16) {
        double v = wsum[t];
        #pragma unroll
        for (int off = 1; off < 16; off <<= 1) {
            double nv = __shfl_up(v, off);
            if (lane >= off) v += nv;
        }
        wsum[t] = v;
    }
    __syncthreads();
    double base = (wid > 0) ? wsum[wid - 1] : 0.0;
    double ex = base + run - part;
    __syncthreads();
    return ex;
}

__global__ __launch_bounds__(1024)
void k_tables(double* __restrict__ expP, double* __restrict__ expM,
              double* __restrict__ gd, double* __restrict__ Ed,
              float* __restrict__ GT, float* __restrict__ GI, float* __restrict__ HI) {
    __shared__ double wsum[16];
    const int t = threadIdx.x;
    const double dx = 14.0 / 7000.0;
    int k0 = t * 7, k1 = k0 + 7;
    if (k1 > TG) k1 = TG;
    if (k0 > TG) k0 = TG;

    for (int k = k0; k < k1; ++k) {
        double x = -10.0 + dx * k;
        expP[k] = exp(x * x);
        expM[k] = exp(-x * x);
    }
    __syncthreads();

    // phase 1: I = exp(-100)/20 + cumtrapz(expM); g = expP * I
    {
        double part = 0.0;
        for (int k = (k0 < 1 ? 1 : k0); k < k1; ++k)
            part += 0.5 * (expM[k - 1] + expM[k]) * dx;
        double run = blk_exscan(part, wsum) + exp(-100.0) / 20.0;
        for (int k = k0; k < k1; ++k) {
            if (k >= 1) run += 0.5 * (expM[k - 1] + expM[k]) * dx;
            double g = expP[k] * run;
            gd[k] = g;
            GT[k] = (float)g;
        }
    }
    __syncthreads();
    // phase 2: G = cumtrapz(g)
    {
        double part = 0.0;
        for (int k = (k0 < 1 ? 1 : k0); k < k1; ++k)
            part += 0.5 * (gd[k - 1] + gd[k]) * dx;
        double run = blk_exscan(part, wsum);
        for (int k = k0; k < k1; ++k) {
            if (k >= 1) run += 0.5 * (gd[k - 1] + gd[k]) * dx;
            GI[k] = (float)run;
        }
    }
    __syncthreads();
    // phase 3: E = cumtrapz(expM * g^2)
    {
        double part = 0.0;
        for (int k = (k0 < 1 ? 1 : k0); k < k1; ++k) {
            double ya = expM[k - 1] * gd[k - 1] * gd[k - 1];
            double yb = expM[k] * gd[k] * gd[k];
            part += 0.5 * (ya + yb) * dx;
        }
        double run = blk_exscan(part, wsum);
        for (int k = k0; k < k1; ++k) {
            if (k >= 1) {
                double ya = expM[k - 1] * gd[k - 1] * gd[k - 1];
                double yb = expM[k] * gd[k] * gd[k];
                run += 0.5 * (ya + yb) * dx;
            }
            Ed[k] = run;
        }
    }
    __syncthreads();
    // phase 4: H = cumtrapz(expP * E)
    {
        double part = 0.0;
        for (int k = (k0 < 1 ? 1 : k0); k < k1; ++k)
            part += 0.5 * (expP[k - 1] * Ed[k - 1] + expP[k] * Ed[k]) * dx;
        double run = blk_exscan(part, wsum);
        for (int k = k0; k < k1; ++k) {
            if (k >= 1) run += 0.5 * (expP[k - 1] * Ed[k - 1] + expP[k] * Ed[k]) * dx;
            HI[k] = (float)run;
        }
    }
}

// ---------------- split kernels ----------------------------------------------
__global__ void k_splitW(const float* __restrict__ W,
                         unsigned short* __restrict__ Wh, unsigned short* __restrict__ Wl) {
    int idx = blockIdx.x * 256 + threadIdx.x;   // 262144
    unsigned short h, l;
    split2(W[idx], h, l);
    Wh[idx] = h; Wl[idx] = l;
}

__global__ void k_splitQ(const float* __restrict__ rho, const float* __restrict__ s,
                         unsigned short* __restrict__ Qh, unsigned short* __restrict__ Ql) {
    size_t idx = (size_t)blockIdx.x * 256 + threadIdx.x;  // 8388608
    int b = (int)(idx >> 18);
    int i = (int)((idx >> 9) & 511);
    int j = (int)(idx & 511);
    float v = rho[idx] * s[b * NN + i] * s[b * NN + j];
    unsigned short h, l;
    split2(v, h, l);
    Qh[idx] = h; Ql[idx] = l;
}

// ---------------- MFMA GEMM: 128x128 tile, BK=32, split-2 bf16 ---------------
// C = A @ B^T with A[i][k] (row-major, split hi/lo) and BT[j][k] (row-major, split).
// MODE 0: write C split-bf16 to Oh/Ol (T1 path).
// MODE 1: rho epilogue, write Q_next = s_next_i s_next_j rho_ij split-bf16.
// MODE 2: rho epilogue, write fp32 rho to Of.
template <int MODE>
__global__ __launch_bounds__(256)
void gemm_mfma(const unsigned short* __restrict__ Ah, const unsigned short* __restrict__ Al,
               long aStride,
               const unsigned short* __restrict__ Bh, const unsigned short* __restrict__ Bl,
               long bStride,
               unsigned short* __restrict__ Oh, unsigned short* __restrict__ Ol,
               float* __restrict__ Of,
               const float* __restrict__ s_lin, const float* __restrict__ chi,
               const float* __restrict__ s_next) {
    __shared__ unsigned short As0[4096], As1[4096], Bs0[4096], Bs1[4096];
    const int b = blockIdx.z;
    const int i0 = blockIdx.y * 128, j0 = blockIdx.x * 128;
    const int tid = threadIdx.x;
    const int w = tid >> 6, lane = tid & 63;
    const int wm = w >> 1, wn = w & 1;

    const unsigned short* Ab_h = Ah + (size_t)b * aStride;
    const unsigned short* Ab_l = Al + (size_t)b * aStride;
    const unsigned short* Bb_h = Bh + (size_t)b * bStride;
    const unsigned short* Bb_l = Bl + (size_t)b * bStride;

    const size_t gA0 = ((size_t)(i0 + (w * 2 + 0) * 16 + (lane >> 2)) << 9) + ((lane & 3) << 3);
    const size_t gA1 = ((size_t)(i0 + (w * 2 + 1) * 16 + (lane >> 2)) << 9) + ((lane & 3) << 3);
    const size_t gB0 = ((size_t)(j0 + (w * 2 + 0) * 16 + (lane >> 2)) << 9) + ((lane & 3) << 3);
    const size_t gB1 = ((size_t)(j0 + (w * 2 + 1) * 16 + (lane >> 2)) << 9) + ((lane & 3) << 3);
    const int lds0 = (w * 2 + 0) * 512;   // ushort index, wave-uniform
    const int lds1 = (w * 2 + 1) * 512;

    f32x4 acc[4][4];
    #pragma unroll
    for (int m = 0; m < 4; ++m)
        #pragma unroll
        for (int n = 0; n < 4; ++n) acc[m][n] = (f32x4){0.f, 0.f, 0.f, 0.f};

    const int kg = lane >> 4;
    int aoff[4], boff[4];
    #pragma unroll
    for (int t = 0; t < 4; ++t) {
        aoff[t] = (wm * 64 + t * 16 + (lane & 15)) * 32 + kg * 8;
        boff[t] = (wn * 64 + t * 16 + (lane & 15)) * 32 + kg * 8;
    }

    for (int k0 = 0; k0 < NN; k0 += 32) {
        GL16(Ab_h + gA0 + k0, As0 + lds0);
        GL16(Ab_h + gA1 + k0, As0 + lds1);
        GL16(Ab_l + gA0 + k0, As1 + lds0);
        GL16(Ab_l + gA1 + k0, As1 + lds1);
        GL16(Bb_h + gB0 + k0, Bs0 + lds0);
        GL16(Bb_h + gB1 + k0, Bs0 + lds1);
        GL16(Bb_l + gB0 + k0, Bs1 + lds0);
        GL16(Bb_l + gB1 + k0, Bs1 + lds1);
        __syncthreads();
        s16x8 ah[4], al[4], bh[4], bl[4];
        #pragma unroll
        for (int t = 0; t < 4; ++t) {
            ah[t] = *reinterpret_cast<const s16x8*>(&As0[aoff[t]]);
            al[t] = *reinterpret_cast<const s16x8*>(&As1[aoff[t]]);
            bh[t] = *reinterpret_cast<const s16x8*>(&Bs0[boff[t]]);
            bl[t] = *reinterpret_cast<const s16x8*>(&Bs1[boff[t]]);
        }
        #pragma unroll
        for (int m = 0; m < 4; ++m)
            #pragma unroll
            for (int n = 0; n < 4; ++n) {
                acc[m][n] = __builtin_amdgcn_mfma_f32_16x16x32_bf16(ah[m], bh[n], acc[m][n], 0, 0, 0);
                acc[m][n] = __builtin_amdgcn_mfma_f32_16x16x32_bf16(ah[m], bl[n], acc[m][n], 0, 0, 0);
                acc[m][n] = __builtin_amdgcn_mfma_f32_16x16x32_bf16(al[m], bh[n], acc[m][n], 0, 0, 0);
            }
        __syncthreads();
    }

    // epilogue — C/D layout: col = lane&15, row = (lane>>4)*4 + reg
    const size_t bofs = (size_t)b * NN * NN;
    const int rb = i0 + wm * 64 + (lane >> 4) * 4;
    const int cb = j0 + wn * 64 + (lane & 15);

    if (MODE == 0) {
        #pragma unroll
        for (int m = 0; m < 4; ++m)
            #pragma unroll
            for (int n = 0; n < 4; ++n) {
                int col = cb + n * 16;
                #pragma unroll
                for (int r = 0; r < 4; ++r) {
                    int row = rb + m * 16 + r;
                    size_t idx = bofs + ((size_t)row << 9) + col;
                    unsigned short h, l;
                    split2(acc[m][n][r], h, l);
                    Oh[idx] = h; Ol[idx] = l;
                }
            }
    } else {
        const float* sl = s_lin + b * NN;
        const float* ch = chi + b * NN;
        float sj[4], cj[4], qj[4];
        #pragma unroll
        for (int n = 0; n < 4; ++n) {
            int col = cb + n * 16;
            sj[n] = sl[col];
            cj[n] = ch[col];
            if (MODE == 1) qj[n] = s_next[b * NN + col];
        }
        #pragma unroll
        for (int m = 0; m < 4; ++m)
            #pragma unroll
            for (int r = 0; r < 4; ++r) {
                int row = rb + m * 16 + r;
                float si = sl[row], ci = ch[row];
                float qi = (MODE == 1) ? s_next[b * NN + row] : 0.f;
                #pragma unroll
                for (int n = 0; n < 4; ++n) {
                    int col = cb + n * 16;
                    float denom = si * sj[n];
                    float rv = (denom > 1e-12f) ? (acc[m][n][r] / fmaxf(denom, 1e-12f)) : 0.0f;
                    rv *= ci * cj[n];
                    if (row == col) rv = 1.0f;
                    size_t idx = bofs + ((size_t)row << 9) + col;
                    if (MODE == 1) {
                        unsigned short h, l;
                        split2(rv * qi * qj[n], h, l);
                        Oh[idx] = h; Ol[idx] = l;
                    } else {
                        Of[idx] = rv;
                    }
                }
            }
    }
}

// ---------------- external pathway -------------------------------------------
__global__ void k_ext_dots(const float* __restrict__ Wx, const float* __restrict__ bx,
                           const float* __restrict__ ux, const float* __restrict__ sx,
                           float* __restrict__ u_e, float* __restrict__ s_e2) {
    int gw = (blockIdx.x << 2) + (threadIdx.x >> 6);
    int lane = threadIdx.x & 63;
    int b = gw >> 9, i = gw & 511;
    const float* wr = Wx + (size_t)i * NN;
    const float* ub = ux + b * NN;
    const float* sb = sx + b * NN;
    float au = 0.0f, as2 = 0.0f;
    for (int j = lane; j < NN; j += 64) {
        float w = wr[j];
        float s = sb[j];
        au = fmaf(w, ub[j], au);
        as2 = fmaf(w * w, s * s, as2);
    }
    #pragma unroll
    for (int off = 32; off; off >>= 1) {
        au += __shfl_down(au, off);
        as2 += __shfl_down(as2, off);
    }
    if (lane == 0) {
        u_e[b * NN + i] = au + bx[i];
        s_e2[b * NN + i] = as2;
    }
}

__global__ void k_ext_stats(float* __restrict__ u_e, float* __restrict__ s_e2,
                            const float* __restrict__ wmx, const float* __restrict__ bmx) {
    int i = blockIdx.x * blockDim.x + threadIdx.x;
    if (i >= NN) return;
    float m = 0.0f;
    for (int b = 0; b < BB; ++b) m += u_e[b * NN + i];
    m *= (1.0f / BB);
    float v = 0.0f;
    for (int b = 0; b < BB; ++b) {
        float d = u_e[b * NN + i] - m;
        v = fmaf(d, d, v);
    }
    v *= (1.0f / BB);
    float f = wmx[i] / sqrtf(v + 1e-5f);
    float bm = bmx[i];
    for (int b = 0; b < BB; ++b) {
        u_e[b * NN + i] = (u_e[b * NN + i] - m) * f + bm;
        s_e2[b * NN + i] *= f * f;
    }
}

// ---------------- per-step u@W^T + diag(C) -----------------------------------
__global__ void k_dots(const float* __restrict__ W, const float* __restrict__ bvec,
                       const float* __restrict__ u,
                       const unsigned short* __restrict__ T1h,
                       const unsigned short* __restrict__ T1l,
                       float* __restrict__ u_lin, float* __restrict__ s_lin) {
    int gw = (blockIdx.x << 2) + (threadIdx.x >> 6);
    int lane = threadIdx.x & 63;
    int b = gw >> 9, i = gw & 511;
    const float* wr = W + (size_t)i * NN;
    const float* ub = u + b * NN;
    const unsigned short* th = T1h + ((size_t)b * NN + i) * NN;
    const unsigned short* tl = T1l + ((size_t)b * NN + i) * NN;
    float au = 0.0f, ad = 0.0f;
    for (int j = lane; j < NN; j += 64) {
        float wv = wr[j];
        au = fmaf(wv, ub[j], au);
        float tv = bf16_f(th[j]) + bf16_f(tl[j]);
        ad = fmaf(wv, tv, ad);
    }
    #pragma unroll
    for (int off = 32; off; off >>= 1) {
        au += __shfl_down(au, off);
        ad += __shfl_down(ad, off);
    }
    if (lane == 0) {
        u_lin[b * NN + i] = au + bvec[i];
        s_lin[b * NN + i] = sqrtf(fmaxf(ad, 0.0f));
    }
}

__global__ void k_stats(const float* __restrict__ u_lin, const float* __restrict__ wm,
                        float* __restrict__ bn_mean, float* __restrict__ bn_f) {
    int i = blockIdx.x * blockDim.x + threadIdx.x;
    if (i >= NN) return;
    float m = 0.0f;
    for (int b = 0; b < BB; ++b) m += u_lin[b * NN + i];
    m *= (1.0f / BB);
    float v = 0.0f;
    for (int b = 0; b < BB; ++b) {
        float d = u_lin[b * NN + i] - m;
        v = fmaf(d, d, v);
    }
    v *= (1.0f / BB);
    bn_mean[i] = m;
    bn_f[i] = wm[i] / sqrtf(v + 1e-5f);
}

__global__ void k_act(const float* __restrict__ u_lin, const float* __restrict__ s_lin,
                      const float* __restrict__ bn_mean, const float* __restrict__ bn_f,
                      const float* __restrict__ b_mean,
                      const float* __restrict__ u_e, const float* __restrict__ s_e2,
                      const float* __restrict__ GT, const float* __restrict__ GI,
                      const float* __restrict__ HI,
                      float* __restrict__ u_out, float* __restrict__ s_out,
                      float* __restrict__ chi) {
    int idx = blockIdx.x * blockDim.x + threadIdx.x;   // 0..16383
    int i = idx & 511;
    const float SQL = 0.22360679774997896f;            // sqrt(0.05)
    float f = bn_f[i];
    float un = (u_lin[idx] - bn_mean[i]) * f + b_mean[i] + u_e[idx];
    float sl = s_lin[idx];
    float sn = sqrtf(sl * sl * f * f + s_e2[idx]);
    float ss = fmaxf(sn, 1e-6f);
    float inv = 1.0f / (ss * SQL);
    float ubx = fminf(fmaxf((1.0f - un) * inv, -10.0f), 4.0f);
    float lbx = fminf(fmaxf((0.0f - un) * inv, -10.0f), 4.0f);
    float dG = interp_tab(GI, ubx) - interp_tab(GI, lbx);
    float ua = 1.0f / (5.0f + 40.0f * dG);
    float dH = fmaxf(interp_tab(HI, ubx) - interp_tab(HI, lbx), 0.0f);
    float sa = sqrtf(3200.0f * dH * ua * ua * ua);
    float dg = interp_tab(GT, ubx) - interp_tab(GT, lbx);
    float ch = ua * ua * 40.0f * dg / (SQL * fmaxf(sa, 1e-9f));
    u_out[idx] = ua;
    s_out[idx] = sa;
    chi[idx] = ch;
}

// ---------------- launcher ---------------------------------------------------
extern "C" void kernel_launch(void* const* d_in, const int* in_sizes, int n_in,
                              void* d_out, int out_size, void* d_ws, size_t ws_size,
                              hipStream_t stream) {
    (void)in_sizes; (void)n_in; (void)out_size; (void)ws_size;
    const float* u_in       = (const float*)d_in[0];
    const float* s_in       = (const float*)d_in[1];
    const float* rho_in     = (const float*)d_in[2];
    const float* u_ext      = (const float*)d_in[3];
    const float* s_ext      = (const float*)d_in[4];
    const float* W          = (const float*)d_in[5];
    const float* bvec       = (const float*)d_in[6];
    const float* W_ext      = (const float*)d_in[7];
    const float* b_ext      = (const float*)d_in[8];
    const float* w_mean     = (const float*)d_in[9];
    const float* b_mean     = (const float*)d_in[10];
    const float* w_mean_ext = (const float*)d_in[11];
    const float* b_mean_ext = (const float*)d_in[12];

    float* out_u   = (float*)d_out;
    float* out_s   = out_u + BB * NN;
    float* out_rho = out_s + BB * NN;
    // Q split-bf16 lives in the out_rho region (scratch until the final step)
    unsigned short* Qh = (unsigned short*)out_rho;
    unsigned short* Ql = Qh + (size_t)BB * NN * NN;

    char* base = (char*)d_ws;
    size_t off = 0;
    auto alloc = [&](size_t bytes) -> char* {
        char* p = base + off;
        off += (bytes + 255) & ~(size_t)255;
        return p;
    };
    unsigned short* T1h = (unsigned short*)alloc((size_t)BB * NN * NN * 2);
    unsigned short* T1l = (unsigned short*)alloc((size_t)BB * NN * NN * 2);
    unsigned short* Wh  = (unsigned short*)alloc((size_t)NN * NN * 2);
    unsigned short* Wl  = (unsigned short*)alloc((size_t)NN * NN * 2);
    double* expP = (double*)alloc(TG * 8);
    double* expM = (double*)alloc(TG * 8);
    double* gd   = (double*)alloc(TG * 8);
    double* Ed   = (double*)alloc(TG * 8);
    float* GTt   = (float*)alloc(TG * 4);
    float* GIt   = (float*)alloc(TG * 4);
    float* HIt   = (float*)alloc(TG * 4);
    float* u_e   = (float*)alloc(BB * NN * 4);
    float* s_e2  = (float*)alloc(BB * NN * 4);
    float* uA    = (float*)alloc(BB * NN * 4);
    float* uB2   = (float*)alloc(BB * NN * 4);
    float* sA    = (float*)alloc(BB * NN * 4);
    float* sB2   = (float*)alloc(BB * NN * 4);
    float* u_lin = (float*)alloc(BB * NN * 4);
    float* s_lin = (float*)alloc(BB * NN * 4);
    float* chi_  = (float*)alloc(BB * NN * 4);
    float* bn_m  = (float*)alloc(NN * 4);
    float* bn_f  = (float*)alloc(NN * 4);

    // prologue
    k_tables<<<1, 1024, 0, stream>>>(expP, expM, gd, Ed, GTt, GIt, HIt);
    k_splitW<<<NN * NN / 256, 256, 0, stream>>>(W, Wh, Wl);
    k_splitQ<<<BB * NN * NN / 256, 256, 0, stream>>>(rho_in, s_in, Qh, Ql);
    k_ext_dots<<<BB * NN / 4, 256, 0, stream>>>(W_ext, b_ext, u_ext, s_ext, u_e, s_e2);
    k_ext_stats<<<2, 256, 0, stream>>>(u_e, s_e2, w_mean_ext, b_mean_ext);

    const float* cu = u_in;
    dim3 gg(NN / 128, NN / 128, BB);   // 4 x 4 x 32

    for (int t = 0; t < SEQ; ++t) {
        // T1 = W @ Q   (A = W split, B^T = Q split)
        gemm_mfma<0><<<gg, 256, 0, stream>>>(
            Wh, Wl, 0L, Qh, Ql, (long)NN * NN, T1h, T1l, nullptr, nullptr, nullptr, nullptr);
        // u_lin = u@W^T + b ; s_lin = sqrt(max(diag(T1 W^T),0))
        k_dots<<<BB * NN / 4, 256, 0, stream>>>(W, bvec, cu, T1h, T1l, u_lin, s_lin);
        k_stats<<<2, 256, 0, stream>>>(u_lin, w_mean, bn_m, bn_f);
        float* nu = (t == SEQ - 1) ? out_u : ((t & 1) ? uA : uB2);
        float* ns = (t == SEQ - 1) ? out_s : ((t & 1) ? sA : sB2);
        k_act<<<BB * NN / 256, 256, 0, stream>>>(
            u_lin, s_lin, bn_m, bn_f, b_mean, u_e, s_e2, GTt, GIt, HIt, nu, ns, chi_);
        // C = T1 @ W^T with rho epilogue
        if (t < SEQ - 1) {
            gemm_mfma<1><<<gg, 256, 0, stream>>>(
                T1h, T1l, (long)NN * NN, Wh, Wl, 0L, Qh, Ql, nullptr, s_lin, chi_, ns);
        } else {
            gemm_mfma<2><<<gg, 256, 0, stream>>>(
                T1h, T1l, (long)NN * NN, Wh, Wl, 0L, nullptr, nullptr, out_rho, s_lin, chi_, nullptr);
        }
        cu = nu;
    }
}